// Round 13
// baseline (280.620 us; speedup 1.0000x reference)
//
#include <hip/hip_runtime.h>

#define DIN 128
#define DH 64
#define DOUT 32
#define BN_EPS 1e-5f

#define BK 128          // nodes per bucket
#define BKSH 7          // log2(BK)
#define NBK_MAX 784     // ceil(100000/128)=782, padded
#define G 128           // counting-sort partition blocks; 16/XCD keeps partial recs lines L2-resident
#define CAP 2560        // fixed per-bucket region capacity (mean 2048, +11 sigma)

typedef __attribute__((ext_vector_type(8))) short short8;
typedef __attribute__((ext_vector_type(4))) float floatx4;

// bf16 helpers (RNE store, exact load)
__device__ __forceinline__ unsigned short f2bf(float f) {
    union { float f; unsigned u; } v; v.f = f;
    unsigned r = (v.u + 0x7FFFu + ((v.u >> 16) & 1u)) >> 16;
    return (unsigned short)r;
}
__device__ __forceinline__ float bf2f(unsigned short h) {
    union { unsigned u; float f; } v; v.u = ((unsigned)h) << 16;
    return v.f;
}
__device__ __forceinline__ float lo_f(unsigned u) {   // bf16 in low ushort -> f32
    union { unsigned u; float f; } v; v.u = u << 16;
    return v.f;
}
__device__ __forceinline__ float hi_f(unsigned u) {   // bf16 in high ushort -> f32
    union { unsigned u; float f; } v; v.u = u & 0xFFFF0000u;
    return v.f;
}
__device__ __forceinline__ unsigned pack2bf(float lo, float hi) {
    return (unsigned)f2bf(lo) | ((unsigned)f2bf(hi) << 16);
}

// ---------------- counting sort pass 1: per-block bucket histogram (g-major write) ----------------

__global__ __launch_bounds__(256) void hist_k(const int* __restrict__ dst, int* __restrict__ hist_g,
                                              int E, int nbk, int chunk) {
    __shared__ int hist[NBK_MAX];
    int g = blockIdx.x, tid = threadIdx.x;
    for (int b = tid; b < nbk; b += 256) hist[b] = 0;
    __syncthreads();
    int i0 = g * chunk, iend = min(i0 + chunk, E);
    for (int i = i0 + tid; i < iend; i += 256)
        atomicAdd(&hist[dst[i] >> BKSH], 1);
    __syncthreads();
    for (int b = tid; b < nbk; b += 256)
        hist_g[(size_t)g * nbk + b] = hist[b];   // coalesced row write
}

// ---------------- pass 2: per-bucket exclusive scan over the G=128 block-counts ----------------
// 16 buckets per block; thread (gl,bl) sums g-slice [gl*8, gl*8+8) -> LDS scan across 16 segments
// -> coalesced g-major rowoff writes. No cross-bucket base (fixed CAP regions).

__global__ __launch_bounds__(256) void scan_k(const int* __restrict__ hist_g, int* __restrict__ rowoff,
                                              int* __restrict__ tot, int nbk) {
    __shared__ int seg[16][17];
    int tid = threadIdx.x;
    int gl = tid >> 4, bl = tid & 15;
    int b = blockIdx.x * 16 + bl;
    bool bok = b < nbk;
    int vals[8];
    int psum = 0;
    #pragma unroll
    for (int j = 0; j < 8; j++) {
        int g = gl * 8 + j;
        int v = bok ? hist_g[(size_t)g * nbk + b] : 0;   // 8 independent loads in flight
        vals[j] = v; psum += v;
    }
    seg[gl][bl] = psum;
    __syncthreads();
    #pragma unroll
    for (int off = 1; off < 16; off <<= 1) {
        int t = (gl >= off) ? seg[gl - off][bl] : 0;
        __syncthreads();
        seg[gl][bl] += t;
        __syncthreads();
    }
    int run = seg[gl][bl] - psum;                        // exclusive base of this 8-g segment
    if (gl == 15 && bok) tot[b] = seg[15][bl];
    #pragma unroll
    for (int j = 0; j < 8; j++) {
        int g = gl * 8 + j;
        if (bok) rowoff[(size_t)g * nbk + b] = run;      // g-major: scatter_k reads rows coalesced
        run += vals[j];
    }
}

// ---------------- pass 3: scatter records into fixed-CAP bucket regions (no global atomics) ----------------

__global__ __launch_bounds__(256) void scatter_k(const int* __restrict__ src, const int* __restrict__ dst,
                                                 const int* __restrict__ rowoff,
                                                 unsigned* __restrict__ recs, int E, int nbk, int chunk) {
    __shared__ int cur[NBK_MAX];
    int g = blockIdx.x, tid = threadIdx.x;
    for (int b = tid; b < nbk; b += 256)
        cur[b] = b * CAP + rowoff[(size_t)g * nbk + b];   // coalesced row read (g-major)
    __syncthreads();
    int i0 = g * chunk, iend = min(i0 + chunk, E);
    for (int i = i0 + tid; i < iend; i += 256) {
        int s = src[i], d = dst[i];
        int b = d >> BKSH;
        int slot = atomicAdd(&cur[b], 1);   // LDS atomic
        if (slot < (b + 1) * CAP)           // overflow guard (never fires at CAP=mean+11sigma)
            recs[slot] = ((unsigned)s << BKSH) | (unsigned)(d & (BK - 1));
    }
}

// ---------------- pass 4: within-bucket node sort -> CSR (col grouped by dst) ----------------

__global__ __launch_bounds__(256) void csr_k(const unsigned* __restrict__ recs, const int* __restrict__ tot,
                                             float* __restrict__ dis, int2* __restrict__ rpde,
                                             int* __restrict__ col, int n) {
    __shared__ int deg[BK], bas[BK], cur[BK], sc[BK];
    int b = blockIdx.x, tid = threadIdx.x;
    if (tid < BK) { deg[tid] = 0; cur[tid] = 0; }
    __syncthreads();
    int lo = b * CAP;
    int hi = lo + min(tot[b], CAP);
    for (int e = lo + tid; e < hi; e += 256)
        atomicAdd(&deg[recs[e] & (BK - 1)], 1);
    __syncthreads();
    if (tid < BK) sc[tid] = deg[tid];
    __syncthreads();
    for (int off = 1; off < BK; off <<= 1) {
        int t = (tid >= off && tid < BK) ? sc[tid - off] : 0;
        __syncthreads();
        if (tid < BK) sc[tid] += t;
        __syncthreads();
    }
    if (tid < BK) {
        bas[tid] = sc[tid] - deg[tid];
        int g = b * BK + tid;
        if (g < n) {
            dis[g] = rsqrtf((float)(deg[tid] + 1));   // +1 self-loop
            rpde[g] = make_int2(lo + bas[tid], deg[tid]);
        }
    }
    __syncthreads();
    for (int e = lo + tid; e < hi; e += 256) {
        unsigned r = recs[e];
        int dl = r & (BK - 1);
        int k = atomicAdd(&cur[dl], 1);
        col[lo + bas[dl] + k] = (int)(r >> BKSH);
    }
}

// ---------------- GEMM1 (MFMA bf16): h1s = bf16((x @ W1) * dis[row]) ----------------

__global__ __launch_bounds__(256) void gemm1_k(const float* __restrict__ x,
                                               const float* __restrict__ W1,
                                               const float* __restrict__ dis,
                                               unsigned short* __restrict__ h1s, int n) {
    __shared__ unsigned short xb[64][136];   // +8 pad: rows 272B apart -> 2-way bank alias (free)
    __shared__ unsigned short wt[64][136];
    int tid = threadIdx.x;
    int r0b = blockIdx.x * 64;

    // stage W1^T: 2048 float4 reads (W1 is L2/L3-resident), transposed bf16 writes
    for (int c = tid; c < 2048; c += 256) {
        int k = c >> 4, n4 = (c & 15) * 4;
        float4 v = ((const float4*)W1)[c];
        wt[n4 + 0][k] = f2bf(v.x);
        wt[n4 + 1][k] = f2bf(v.y);
        wt[n4 + 2][k] = f2bf(v.z);
        wt[n4 + 3][k] = f2bf(v.w);
    }
    // stage x tile fp32 -> bf16
    for (int c = tid; c < 2048; c += 256) {
        int r = c >> 5, k4 = (c & 31) * 4;
        int gr = r0b + r;
        float4 v = make_float4(0.f, 0.f, 0.f, 0.f);
        if (gr < n) v = ((const float4*)x)[(gr << 5) + (k4 >> 2)];
        ushort4 o;
        o.x = f2bf(v.x); o.y = f2bf(v.y); o.z = f2bf(v.z); o.w = f2bf(v.w);
        *(ushort4*)&xb[r][k4] = o;
    }
    __syncthreads();

    int w = tid >> 6, lane = tid & 63;
    int rr = lane & 15, q = lane >> 4;
    floatx4 acc0 = {0.f, 0.f, 0.f, 0.f}, acc1 = acc0, acc2 = acc0, acc3 = acc0;
    #pragma unroll
    for (int kt = 0; kt < 4; kt++) {
        int k0 = kt * 32 + q * 8;
        short8 a  = *(const short8*)&xb[w * 16 + rr][k0];
        short8 b0 = *(const short8*)&wt[rr][k0];
        short8 b1 = *(const short8*)&wt[16 + rr][k0];
        short8 b2 = *(const short8*)&wt[32 + rr][k0];
        short8 b3 = *(const short8*)&wt[48 + rr][k0];
        acc0 = __builtin_amdgcn_mfma_f32_16x16x32_bf16(a, b0, acc0, 0, 0, 0);
        acc1 = __builtin_amdgcn_mfma_f32_16x16x32_bf16(a, b1, acc1, 0, 0, 0);
        acc2 = __builtin_amdgcn_mfma_f32_16x16x32_bf16(a, b2, acc2, 0, 0, 0);
        acc3 = __builtin_amdgcn_mfma_f32_16x16x32_bf16(a, b3, acc3, 0, 0, 0);
    }
    #pragma unroll
    for (int t = 0; t < 4; t++) {
        int gr = r0b + w * 16 + q * 4 + t;
        if (gr < n) {
            float dd = dis[gr];
            unsigned short* o = &h1s[gr * 64];
            o[rr]      = f2bf(acc0[t] * dd);
            o[16 + rr] = f2bf(acc1[t] * dd);
            o[32 + rr] = f2bf(acc2[t] * dd);
            o[48 + rr] = f2bf(acc3[t] * dd);
        }
    }
}

// ---------------- Aggregation layer 1: wave per node, uint-packed (2 feats/lane, 2 edges/instr) ----------------

__global__ __launch_bounds__(256) void agg1_k(const unsigned* __restrict__ h1p,
                                              const int2* __restrict__ rpde,
                                              const int* __restrict__ col,
                                              unsigned* __restrict__ outp, int n) {
    int node = (blockIdx.x * 256 + threadIdx.x) >> 6;
    int lane = threadIdx.x & 63;
    if (node >= n) return;
    int f2 = lane & 31, eslot = lane >> 5;
    int2 rd = rpde[node];
    int e  = __builtin_amdgcn_readfirstlane(rd.x);
    int dg = __builtin_amdgcn_readfirstlane(rd.y);

    float lo0 = 0.f, lo1 = 0.f, lo2 = 0.f, lo3 = 0.f, lo4 = 0.f, lo5 = 0.f, lo6 = 0.f, lo7 = 0.f;
    float hi0 = 0.f, hi1 = 0.f, hi2 = 0.f, hi3 = 0.f, hi4 = 0.f, hi5 = 0.f, hi6 = 0.f, hi7 = 0.f;
    int b = 0;
    for (; b + 16 <= dg; b += 16) {
        int s0 = col[e + b + 0 + eslot],  s1 = col[e + b + 2 + eslot];
        int s2 = col[e + b + 4 + eslot],  s3 = col[e + b + 6 + eslot];
        int s4 = col[e + b + 8 + eslot],  s5 = col[e + b + 10 + eslot];
        int s6 = col[e + b + 12 + eslot], s7 = col[e + b + 14 + eslot];
        unsigned u0 = h1p[s0 * 32 + f2], u1 = h1p[s1 * 32 + f2];
        unsigned u2 = h1p[s2 * 32 + f2], u3 = h1p[s3 * 32 + f2];
        unsigned u4 = h1p[s4 * 32 + f2], u5 = h1p[s5 * 32 + f2];
        unsigned u6 = h1p[s6 * 32 + f2], u7 = h1p[s7 * 32 + f2];
        lo0 += lo_f(u0); hi0 += hi_f(u0);
        lo1 += lo_f(u1); hi1 += hi_f(u1);
        lo2 += lo_f(u2); hi2 += hi_f(u2);
        lo3 += lo_f(u3); hi3 += hi_f(u3);
        lo4 += lo_f(u4); hi4 += hi_f(u4);
        lo5 += lo_f(u5); hi5 += hi_f(u5);
        lo6 += lo_f(u6); hi6 += hi_f(u6);
        lo7 += lo_f(u7); hi7 += hi_f(u7);
    }
    if (b < dg) {
        int last = dg - 1;
        int i0 = b + 0 + eslot,  i1 = b + 2 + eslot,  i2 = b + 4 + eslot,  i3 = b + 6 + eslot;
        int i4 = b + 8 + eslot,  i5 = b + 10 + eslot, i6 = b + 12 + eslot, i7 = b + 14 + eslot;
        int s0 = col[e + min(i0, last)], s1 = col[e + min(i1, last)];
        int s2 = col[e + min(i2, last)], s3 = col[e + min(i3, last)];
        int s4 = col[e + min(i4, last)], s5 = col[e + min(i5, last)];
        int s6 = col[e + min(i6, last)], s7 = col[e + min(i7, last)];
        unsigned u0 = h1p[s0 * 32 + f2], u1 = h1p[s1 * 32 + f2];
        unsigned u2 = h1p[s2 * 32 + f2], u3 = h1p[s3 * 32 + f2];
        unsigned u4 = h1p[s4 * 32 + f2], u5 = h1p[s5 * 32 + f2];
        unsigned u6 = h1p[s6 * 32 + f2], u7 = h1p[s7 * 32 + f2];
        lo0 += (i0 < dg) ? lo_f(u0) : 0.f; hi0 += (i0 < dg) ? hi_f(u0) : 0.f;
        lo1 += (i1 < dg) ? lo_f(u1) : 0.f; hi1 += (i1 < dg) ? hi_f(u1) : 0.f;
        lo2 += (i2 < dg) ? lo_f(u2) : 0.f; hi2 += (i2 < dg) ? hi_f(u2) : 0.f;
        lo3 += (i3 < dg) ? lo_f(u3) : 0.f; hi3 += (i3 < dg) ? hi_f(u3) : 0.f;
        lo4 += (i4 < dg) ? lo_f(u4) : 0.f; hi4 += (i4 < dg) ? hi_f(u4) : 0.f;
        lo5 += (i5 < dg) ? lo_f(u5) : 0.f; hi5 += (i5 < dg) ? hi_f(u5) : 0.f;
        lo6 += (i6 < dg) ? lo_f(u6) : 0.f; hi6 += (i6 < dg) ? hi_f(u6) : 0.f;
        lo7 += (i7 < dg) ? lo_f(u7) : 0.f; hi7 += (i7 < dg) ? hi_f(u7) : 0.f;
    }
    float lo = ((lo0 + lo1) + (lo2 + lo3)) + ((lo4 + lo5) + (lo6 + lo7));
    float hi = ((hi0 + hi1) + (hi2 + hi3)) + ((hi4 + hi5) + (hi6 + hi7));
    lo += __shfl_xor(lo, 32, 64);
    hi += __shfl_xor(hi, 32, 64);
    if (eslot == 0) {
        unsigned us = h1p[node * 32 + f2];
        float dn = rsqrtf((float)(dg + 1));
        outp[node * 32 + f2] = pack2bf((lo + lo_f(us)) * dn, (hi + hi_f(us)) * dn);
    }
}

// ---------------- BN stats (bf16 input) ----------------

__global__ __launch_bounds__(256) void bnstats_k(const unsigned short* __restrict__ agg1b,
                                                 float* __restrict__ stats, int n) {
    int f = threadIdx.x & 63, g = threadIdx.x >> 6;
    float sum = 0.f, sq = 0.f;
    for (int r = blockIdx.x * 4 + g; r < n; r += gridDim.x * 4) {
        float v = bf2f(agg1b[r * 64 + f]);
        sum += v; sq += v * v;
    }
    __shared__ float s1[4][64], s2[4][64];
    s1[g][f] = sum; s2[g][f] = sq;
    __syncthreads();
    if (g == 0) {
        sum = s1[0][f] + s1[1][f] + s1[2][f] + s1[3][f];
        sq  = s2[0][f] + s2[1][f] + s2[2][f] + s2[3][f];
        atomicAdd(&stats[f], sum);
        atomicAdd(&stats[64 + f], sq);
    }
}

// ---------------- GEMM2 (MFMA bf16), BN fold inlined: h2s = bf16((relu(agg1b*s+t) @ W2) * dis[row]) ----------------

__global__ __launch_bounds__(256) void gemm2_k(const unsigned short* __restrict__ agg1b,
                                               const float* __restrict__ W2,
                                               const float* __restrict__ stats,
                                               const float* __restrict__ gamma, const float* __restrict__ beta,
                                               const float* __restrict__ dis,
                                               unsigned short* __restrict__ h2s, float invn, int n) {
    __shared__ unsigned short ab[64][72];    // +8 pad
    __shared__ unsigned short wt[32][72];
    __shared__ float s_s[64], s_t[64];
    int tid = threadIdx.x;
    int r0b = blockIdx.x * 64;
    if (tid < 64) {                          // BN fold (b1 cancels by shift invariance)
        float mean = stats[tid] * invn;
        float var = stats[64 + tid] * invn - mean * mean;
        float s = gamma[tid] * rsqrtf(var + BN_EPS);
        s_s[tid] = s;
        s_t[tid] = beta[tid] - mean * s;
    }
    for (int c = tid; c < 512; c += 256) {   // stage W2^T (512 float4)
        int k = c >> 3, n4 = (c & 7) * 4;
        float4 v = ((const float4*)W2)[c];
        wt[n4 + 0][k] = f2bf(v.x);
        wt[n4 + 1][k] = f2bf(v.y);
        wt[n4 + 2][k] = f2bf(v.z);
        wt[n4 + 3][k] = f2bf(v.w);
    }
    __syncthreads();
    for (int c = tid; c < 512; c += 256) {
        int r = c >> 3, k0 = (c & 7) * 8;
        int gr = r0b + r;
        unsigned short tmp[8];
        if (gr < n) {
            const unsigned short* ap = &agg1b[gr * 64 + k0];
            #pragma unroll
            for (int j = 0; j < 8; j++)
                tmp[j] = f2bf(fmaxf(bf2f(ap[j]) * s_s[k0 + j] + s_t[k0 + j], 0.f));
        } else {
            #pragma unroll
            for (int j = 0; j < 8; j++) tmp[j] = 0;
        }
        *(short8*)&ab[r][k0] = *(short8*)tmp;
    }
    __syncthreads();

    int w = tid >> 6, lane = tid & 63;
    int rr = lane & 15, q = lane >> 4;
    floatx4 acc0 = {0.f, 0.f, 0.f, 0.f}, acc1 = acc0;
    #pragma unroll
    for (int kt = 0; kt < 2; kt++) {
        int k0 = kt * 32 + q * 8;
        short8 a  = *(const short8*)&ab[w * 16 + rr][k0];
        short8 b0 = *(const short8*)&wt[rr][k0];
        short8 b1 = *(const short8*)&wt[16 + rr][k0];
        acc0 = __builtin_amdgcn_mfma_f32_16x16x32_bf16(a, b0, acc0, 0, 0, 0);
        acc1 = __builtin_amdgcn_mfma_f32_16x16x32_bf16(a, b1, acc1, 0, 0, 0);
    }
    #pragma unroll
    for (int t = 0; t < 4; t++) {
        int gr = r0b + w * 16 + q * 4 + t;
        if (gr < n) {
            float dd = dis[gr];
            h2s[gr * 32 + rr]      = f2bf(acc0[t] * dd);
            h2s[gr * 32 + 16 + rr] = f2bf(acc1[t] * dd);
        }
    }
}

// ---------------- Aggregation layer 2: node per half-wave, uint-packed (2 feats/lane, 2 edges/instr) ----------------

__global__ __launch_bounds__(256) void agg2_k(const unsigned* __restrict__ h2p,
                                              const int2* __restrict__ rpde,
                                              const int* __restrict__ col, const float* __restrict__ b2,
                                              float* __restrict__ out, int n) {
    int wave = (blockIdx.x * 256 + threadIdx.x) >> 6;
    int lane = threadIdx.x & 63;
    int half = lane >> 5, hl = lane & 31;
    int node = wave * 2 + half;
    if (node >= n) return;
    int f2 = hl & 15, eslot = hl >> 4;
    int2 rd = rpde[node];                    // uniform within half
    int e = rd.x, dg = rd.y;

    float lo0 = 0.f, lo1 = 0.f, lo2 = 0.f, lo3 = 0.f, lo4 = 0.f, lo5 = 0.f, lo6 = 0.f, lo7 = 0.f;
    float hi0 = 0.f, hi1 = 0.f, hi2 = 0.f, hi3 = 0.f, hi4 = 0.f, hi5 = 0.f, hi6 = 0.f, hi7 = 0.f;
    int b = 0;
    for (; b + 16 <= dg; b += 16) {
        int s0 = col[e + b + 0 + eslot],  s1 = col[e + b + 2 + eslot];
        int s2 = col[e + b + 4 + eslot],  s3 = col[e + b + 6 + eslot];
        int s4 = col[e + b + 8 + eslot],  s5 = col[e + b + 10 + eslot];
        int s6 = col[e + b + 12 + eslot], s7 = col[e + b + 14 + eslot];
        unsigned u0 = h2p[s0 * 16 + f2], u1 = h2p[s1 * 16 + f2];
        unsigned u2 = h2p[s2 * 16 + f2], u3 = h2p[s3 * 16 + f2];
        unsigned u4 = h2p[s4 * 16 + f2], u5 = h2p[s5 * 16 + f2];
        unsigned u6 = h2p[s6 * 16 + f2], u7 = h2p[s7 * 16 + f2];
        lo0 += lo_f(u0); hi0 += hi_f(u0);
        lo1 += lo_f(u1); hi1 += hi_f(u1);
        lo2 += lo_f(u2); hi2 += hi_f(u2);
        lo3 += lo_f(u3); hi3 += hi_f(u3);
        lo4 += lo_f(u4); hi4 += hi_f(u4);
        lo5 += lo_f(u5); hi5 += hi_f(u5);
        lo6 += lo_f(u6); hi6 += hi_f(u6);
        lo7 += lo_f(u7); hi7 += hi_f(u7);
    }
    if (b < dg) {
        int last = dg - 1;
        int i0 = b + 0 + eslot,  i1 = b + 2 + eslot,  i2 = b + 4 + eslot,  i3 = b + 6 + eslot;
        int i4 = b + 8 + eslot,  i5 = b + 10 + eslot, i6 = b + 12 + eslot, i7 = b + 14 + eslot;
        int s0 = col[e + min(i0, last)], s1 = col[e + min(i1, last)];
        int s2 = col[e + min(i2, last)], s3 = col[e + min(i3, last)];
        int s4 = col[e + min(i4, last)], s5 = col[e + min(i5, last)];
        int s6 = col[e + min(i6, last)], s7 = col[e + min(i7, last)];
        unsigned u0 = h2p[s0 * 16 + f2], u1 = h2p[s1 * 16 + f2];
        unsigned u2 = h2p[s2 * 16 + f2], u3 = h2p[s3 * 16 + f2];
        unsigned u4 = h2p[s4 * 16 + f2], u5 = h2p[s5 * 16 + f2];
        unsigned u6 = h2p[s6 * 16 + f2], u7 = h2p[s7 * 16 + f2];
        lo0 += (i0 < dg) ? lo_f(u0) : 0.f; hi0 += (i0 < dg) ? hi_f(u0) : 0.f;
        lo1 += (i1 < dg) ? lo_f(u1) : 0.f; hi1 += (i1 < dg) ? hi_f(u1) : 0.f;
        lo2 += (i2 < dg) ? lo_f(u2) : 0.f; hi2 += (i2 < dg) ? hi_f(u2) : 0.f;
        lo3 += (i3 < dg) ? lo_f(u3) : 0.f; hi3 += (i3 < dg) ? hi_f(u3) : 0.f;
        lo4 += (i4 < dg) ? lo_f(u4) : 0.f; hi4 += (i4 < dg) ? hi_f(u4) : 0.f;
        lo5 += (i5 < dg) ? lo_f(u5) : 0.f; hi5 += (i5 < dg) ? hi_f(u5) : 0.f;
        lo6 += (i6 < dg) ? lo_f(u6) : 0.f; hi6 += (i6 < dg) ? hi_f(u6) : 0.f;
        lo7 += (i7 < dg) ? lo_f(u7) : 0.f; hi7 += (i7 < dg) ? hi_f(u7) : 0.f;
    }
    float lo = ((lo0 + lo1) + (lo2 + lo3)) + ((lo4 + lo5) + (lo6 + lo7));
    float hi = ((hi0 + hi1) + (hi2 + hi3)) + ((hi4 + hi5) + (hi6 + hi7));
    lo += __shfl_xor(lo, 16, 64);            // cross-eslot within the 32-lane half
    hi += __shfl_xor(hi, 16, 64);
    if (eslot == 0) {
        unsigned us = h2p[node * 16 + f2];
        float dn = rsqrtf((float)(dg + 1));
        float2 bb = ((const float2*)b2)[f2];
        float2 o;
        o.x = (lo + lo_f(us)) * dn + bb.x;
        o.y = (hi + hi_f(us)) * dn + bb.y;
        ((float2*)out)[node * 16 + f2] = o;
    }
}

// ---------------- launch ----------------

extern "C" void kernel_launch(void* const* d_in, const int* in_sizes, int n_in,
                              void* d_out, int out_size, void* d_ws, size_t ws_size,
                              hipStream_t stream) {
    const float* x      = (const float*)d_in[0];
    const int*   ei     = (const int*)d_in[1];
    const float* W1     = (const float*)d_in[2];
    // d_in[3] = b1 (cancels inside BN)
    const float* gamma1 = (const float*)d_in[4];
    const float* beta1  = (const float*)d_in[5];
    const float* W2     = (const float*)d_in[6];
    const float* b2     = (const float*)d_in[7];
    float* out = (float*)d_out;

    int N = in_sizes[0] / DIN;
    int E = in_sizes[1] / 2;
    const int* src = ei;
    const int* dst = ei + E;
    int nbk = (N + BK - 1) >> BKSH;         // 782
    int chunk = (E + G - 1) / G;

    size_t off = 0;  // 4B units
    auto alloc = [&](size_t elems) -> void* {
        void* p = (char*)d_ws + off * 4;
        off += (elems + 127) & ~size_t(127);
        return p;
    };
    int*            hist_g = (int*)alloc((size_t)G * NBK_MAX);
    int*            rowoff = (int*)alloc((size_t)G * NBK_MAX);            // g-major [G][nbk]
    int*            tot    = (int*)alloc(NBK_MAX);
    unsigned*       recs   = (unsigned*)alloc((size_t)NBK_MAX * CAP);     // fixed-CAP regions
    int*            col    = (int*)alloc((size_t)NBK_MAX * CAP);
    float*          dis    = (float*)alloc(N);
    int2*           rpde   = (int2*)alloc((size_t)N * 2);
    float*          stats  = (float*)alloc(128);
    unsigned short* h1s    = (unsigned short*)alloc((size_t)N * DH / 2);  // bf16
    unsigned short* agg1b  = (unsigned short*)alloc((size_t)N * DH / 2);  // bf16
    unsigned short* h2s    = h1s;  // h1s dead after agg1_k

    hipMemsetAsync(stats, 0, 128 * sizeof(float), stream);

    hist_k<<<G, 256, 0, stream>>>(dst, hist_g, E, nbk, chunk);
    scan_k<<<(nbk + 15) / 16, 256, 0, stream>>>(hist_g, rowoff, tot, nbk);
    scatter_k<<<G, 256, 0, stream>>>(src, dst, rowoff, recs, E, nbk, chunk);
    csr_k<<<nbk, 256, 0, stream>>>(recs, tot, dis, rpde, col, N);

    gemm1_k<<<(N + 63) / 64, 256, 0, stream>>>(x, W1, dis, h1s, N);
    agg1_k<<<(N + 3) / 4, 256, 0, stream>>>((const unsigned*)h1s, rpde, col, (unsigned*)agg1b, N);

    bnstats_k<<<400, 256, 0, stream>>>(agg1b, stats, N);

    gemm2_k<<<(N + 63) / 64, 256, 0, stream>>>(agg1b, W2, stats, gamma1, beta1, dis, h2s,
                                               1.0f / (float)N, N);
    agg2_k<<<(N + 7) / 8, 256, 0, stream>>>((const unsigned*)h2s, rpde, col, b2, out, N);
}

// Round 14
// 254.325 us; speedup vs baseline: 1.1034x; 1.1034x over previous
//
#include <hip/hip_runtime.h>

#define DIN 128
#define DH 64
#define DOUT 32
#define BN_EPS 1e-5f

#define BK 128          // nodes per bucket
#define BKSH 7          // log2(BK)
#define NBK_MAX 784     // ceil(100000/128)=782, padded
#define G 256           // counting-sort partition blocks; 32/XCD open-line set ~3.2MB fits L2
#define CAP 2560        // fixed per-bucket region capacity (mean 2048, +11 sigma)

typedef __attribute__((ext_vector_type(8))) short short8;
typedef __attribute__((ext_vector_type(4))) float floatx4;

// bf16 helpers (RNE store, exact load)
__device__ __forceinline__ unsigned short f2bf(float f) {
    union { float f; unsigned u; } v; v.f = f;
    unsigned r = (v.u + 0x7FFFu + ((v.u >> 16) & 1u)) >> 16;
    return (unsigned short)r;
}
__device__ __forceinline__ float bf2f(unsigned short h) {
    union { unsigned u; float f; } v; v.u = ((unsigned)h) << 16;
    return v.f;
}
__device__ __forceinline__ float lo_f(unsigned u) {
    union { unsigned u; float f; } v; v.u = u << 16;
    return v.f;
}
__device__ __forceinline__ float hi_f(unsigned u) {
    union { unsigned u; float f; } v; v.u = u & 0xFFFF0000u;
    return v.f;
}
__device__ __forceinline__ unsigned pack2bf(float lo, float hi) {
    return (unsigned)f2bf(lo) | ((unsigned)f2bf(hi) << 16);
}

// ---------------- counting sort pass 1: per-block bucket histogram (g-major write) ----------------

__global__ __launch_bounds__(512) void hist_k(const int* __restrict__ dst, int* __restrict__ hist_g,
                                              int E, int nbk, int chunk) {
    __shared__ int hist[NBK_MAX];
    int g = blockIdx.x, tid = threadIdx.x;
    for (int b = tid; b < nbk; b += 512) hist[b] = 0;
    __syncthreads();
    int i0 = g * chunk, iend = min(i0 + chunk, E);
    for (int i = i0 + tid; i < iend; i += 512)
        atomicAdd(&hist[dst[i] >> BKSH], 1);
    __syncthreads();
    for (int b = tid; b < nbk; b += 512)
        hist_g[(size_t)g * nbk + b] = hist[b];   // coalesced row write
}

// ---------------- pass 2: per-bucket exclusive scan over the G=256 block-counts ----------------
// 16 buckets per block; thread (gl,bl) sums g-slice [gl*16, gl*16+16) -> LDS scan across 16
// segments -> coalesced g-major rowoff writes. No cross-bucket base (fixed CAP regions).

__global__ __launch_bounds__(256) void scan_k(const int* __restrict__ hist_g, int* __restrict__ rowoff,
                                              int* __restrict__ tot, int nbk) {
    __shared__ int seg[16][17];
    int tid = threadIdx.x;
    int gl = tid >> 4, bl = tid & 15;
    int b = blockIdx.x * 16 + bl;
    bool bok = b < nbk;
    int vals[16];
    int psum = 0;
    #pragma unroll
    for (int j = 0; j < 16; j++) {
        int g = gl * 16 + j;
        int v = bok ? hist_g[(size_t)g * nbk + b] : 0;   // 16 independent loads in flight
        vals[j] = v; psum += v;
    }
    seg[gl][bl] = psum;
    __syncthreads();
    #pragma unroll
    for (int off = 1; off < 16; off <<= 1) {
        int t = (gl >= off) ? seg[gl - off][bl] : 0;
        __syncthreads();
        seg[gl][bl] += t;
        __syncthreads();
    }
    int run = seg[gl][bl] - psum;                        // exclusive base of this 16-g segment
    if (gl == 15 && bok) tot[b] = seg[15][bl];
    #pragma unroll
    for (int j = 0; j < 16; j++) {
        int g = gl * 16 + j;
        if (bok) rowoff[(size_t)g * nbk + b] = run;      // g-major: scatter_k reads rows coalesced
        run += vals[j];
    }
}

// ---------------- pass 3: scatter records into fixed-CAP bucket regions (no global atomics) ----------------

__global__ __launch_bounds__(512) void scatter_k(const int* __restrict__ src, const int* __restrict__ dst,
                                                 const int* __restrict__ rowoff,
                                                 unsigned* __restrict__ recs, int E, int nbk, int chunk) {
    __shared__ int cur[NBK_MAX];
    int g = blockIdx.x, tid = threadIdx.x;
    for (int b = tid; b < nbk; b += 512)
        cur[b] = b * CAP + rowoff[(size_t)g * nbk + b];   // coalesced row read (g-major)
    __syncthreads();
    int i0 = g * chunk, iend = min(i0 + chunk, E);
    for (int i = i0 + tid; i < iend; i += 512) {
        int s = src[i], d = dst[i];
        int b = d >> BKSH;
        int slot = atomicAdd(&cur[b], 1);   // LDS atomic
        if (slot < (b + 1) * CAP)           // overflow guard (never fires at CAP=mean+11sigma)
            recs[slot] = ((unsigned)s << BKSH) | (unsigned)(d & (BK - 1));
    }
}

// ---------------- pass 4: within-bucket node sort -> CSR (col grouped by dst) ----------------

__global__ __launch_bounds__(256) void csr_k(const unsigned* __restrict__ recs, const int* __restrict__ tot,
                                             float* __restrict__ dis, int2* __restrict__ rpde,
                                             int* __restrict__ col, int n) {
    __shared__ int deg[BK], bas[BK], cur[BK], sc[BK];
    int b = blockIdx.x, tid = threadIdx.x;
    if (tid < BK) { deg[tid] = 0; cur[tid] = 0; }
    __syncthreads();
    int lo = b * CAP;
    int hi = lo + min(tot[b], CAP);
    for (int e = lo + tid; e < hi; e += 256)
        atomicAdd(&deg[recs[e] & (BK - 1)], 1);
    __syncthreads();
    if (tid < BK) sc[tid] = deg[tid];
    __syncthreads();
    for (int off = 1; off < BK; off <<= 1) {
        int t = (tid >= off && tid < BK) ? sc[tid - off] : 0;
        __syncthreads();
        if (tid < BK) sc[tid] += t;
        __syncthreads();
    }
    if (tid < BK) {
        bas[tid] = sc[tid] - deg[tid];
        int g = b * BK + tid;
        if (g < n) {
            dis[g] = rsqrtf((float)(deg[tid] + 1));   // +1 self-loop
            rpde[g] = make_int2(lo + bas[tid], deg[tid]);
        }
    }
    __syncthreads();
    for (int e = lo + tid; e < hi; e += 256) {
        unsigned r = recs[e];
        int dl = r & (BK - 1);
        int k = atomicAdd(&cur[dl], 1);
        col[lo + bas[dl] + k] = (int)(r >> BKSH);
    }
}

// ---------------- GEMM1 (MFMA bf16): h1s = bf16((x @ W1) * dis[row]) ----------------

__global__ __launch_bounds__(256) void gemm1_k(const float* __restrict__ x,
                                               const float* __restrict__ W1,
                                               const float* __restrict__ dis,
                                               unsigned short* __restrict__ h1s, int n) {
    __shared__ unsigned short xb[64][136];   // +8 pad: rows 272B apart -> 2-way bank alias (free)
    __shared__ unsigned short wt[64][136];
    int tid = threadIdx.x;
    int r0b = blockIdx.x * 64;

    for (int c = tid; c < 2048; c += 256) {
        int k = c >> 4, n4 = (c & 15) * 4;
        float4 v = ((const float4*)W1)[c];
        wt[n4 + 0][k] = f2bf(v.x);
        wt[n4 + 1][k] = f2bf(v.y);
        wt[n4 + 2][k] = f2bf(v.z);
        wt[n4 + 3][k] = f2bf(v.w);
    }
    for (int c = tid; c < 2048; c += 256) {
        int r = c >> 5, k4 = (c & 31) * 4;
        int gr = r0b + r;
        float4 v = make_float4(0.f, 0.f, 0.f, 0.f);
        if (gr < n) v = ((const float4*)x)[(gr << 5) + (k4 >> 2)];
        ushort4 o;
        o.x = f2bf(v.x); o.y = f2bf(v.y); o.z = f2bf(v.z); o.w = f2bf(v.w);
        *(ushort4*)&xb[r][k4] = o;
    }
    __syncthreads();

    int w = tid >> 6, lane = tid & 63;
    int rr = lane & 15, q = lane >> 4;
    floatx4 acc0 = {0.f, 0.f, 0.f, 0.f}, acc1 = acc0, acc2 = acc0, acc3 = acc0;
    #pragma unroll
    for (int kt = 0; kt < 4; kt++) {
        int k0 = kt * 32 + q * 8;
        short8 a  = *(const short8*)&xb[w * 16 + rr][k0];
        short8 b0 = *(const short8*)&wt[rr][k0];
        short8 b1 = *(const short8*)&wt[16 + rr][k0];
        short8 b2 = *(const short8*)&wt[32 + rr][k0];
        short8 b3 = *(const short8*)&wt[48 + rr][k0];
        acc0 = __builtin_amdgcn_mfma_f32_16x16x32_bf16(a, b0, acc0, 0, 0, 0);
        acc1 = __builtin_amdgcn_mfma_f32_16x16x32_bf16(a, b1, acc1, 0, 0, 0);
        acc2 = __builtin_amdgcn_mfma_f32_16x16x32_bf16(a, b2, acc2, 0, 0, 0);
        acc3 = __builtin_amdgcn_mfma_f32_16x16x32_bf16(a, b3, acc3, 0, 0, 0);
    }
    #pragma unroll
    for (int t = 0; t < 4; t++) {
        int gr = r0b + w * 16 + q * 4 + t;
        if (gr < n) {
            float dd = dis[gr];
            unsigned short* o = &h1s[gr * 64];
            o[rr]      = f2bf(acc0[t] * dd);
            o[16 + rr] = f2bf(acc1[t] * dd);
            o[32 + rr] = f2bf(acc2[t] * dd);
            o[48 + rr] = f2bf(acc3[t] * dd);
        }
    }
}

// ---------------- Aggregation layer 1: wave per node, uint-packed (2 feats/lane, 2 edges/instr) ----------------

__global__ __launch_bounds__(256) void agg1_k(const unsigned* __restrict__ h1p,
                                              const int2* __restrict__ rpde,
                                              const int* __restrict__ col,
                                              unsigned* __restrict__ outp, int n) {
    int node = (blockIdx.x * 256 + threadIdx.x) >> 6;
    int lane = threadIdx.x & 63;
    if (node >= n) return;
    int f2 = lane & 31, eslot = lane >> 5;
    int2 rd = rpde[node];
    int e  = __builtin_amdgcn_readfirstlane(rd.x);
    int dg = __builtin_amdgcn_readfirstlane(rd.y);

    float lo0 = 0.f, lo1 = 0.f, lo2 = 0.f, lo3 = 0.f, lo4 = 0.f, lo5 = 0.f, lo6 = 0.f, lo7 = 0.f;
    float hi0 = 0.f, hi1 = 0.f, hi2 = 0.f, hi3 = 0.f, hi4 = 0.f, hi5 = 0.f, hi6 = 0.f, hi7 = 0.f;
    int b = 0;
    for (; b + 16 <= dg; b += 16) {
        int s0 = col[e + b + 0 + eslot],  s1 = col[e + b + 2 + eslot];
        int s2 = col[e + b + 4 + eslot],  s3 = col[e + b + 6 + eslot];
        int s4 = col[e + b + 8 + eslot],  s5 = col[e + b + 10 + eslot];
        int s6 = col[e + b + 12 + eslot], s7 = col[e + b + 14 + eslot];
        unsigned u0 = h1p[s0 * 32 + f2], u1 = h1p[s1 * 32 + f2];
        unsigned u2 = h1p[s2 * 32 + f2], u3 = h1p[s3 * 32 + f2];
        unsigned u4 = h1p[s4 * 32 + f2], u5 = h1p[s5 * 32 + f2];
        unsigned u6 = h1p[s6 * 32 + f2], u7 = h1p[s7 * 32 + f2];
        lo0 += lo_f(u0); hi0 += hi_f(u0);
        lo1 += lo_f(u1); hi1 += hi_f(u1);
        lo2 += lo_f(u2); hi2 += hi_f(u2);
        lo3 += lo_f(u3); hi3 += hi_f(u3);
        lo4 += lo_f(u4); hi4 += hi_f(u4);
        lo5 += lo_f(u5); hi5 += hi_f(u5);
        lo6 += lo_f(u6); hi6 += hi_f(u6);
        lo7 += lo_f(u7); hi7 += hi_f(u7);
    }
    if (b < dg) {
        int last = dg - 1;
        int i0 = b + 0 + eslot,  i1 = b + 2 + eslot,  i2 = b + 4 + eslot,  i3 = b + 6 + eslot;
        int i4 = b + 8 + eslot,  i5 = b + 10 + eslot, i6 = b + 12 + eslot, i7 = b + 14 + eslot;
        int s0 = col[e + min(i0, last)], s1 = col[e + min(i1, last)];
        int s2 = col[e + min(i2, last)], s3 = col[e + min(i3, last)];
        int s4 = col[e + min(i4, last)], s5 = col[e + min(i5, last)];
        int s6 = col[e + min(i6, last)], s7 = col[e + min(i7, last)];
        unsigned u0 = h1p[s0 * 32 + f2], u1 = h1p[s1 * 32 + f2];
        unsigned u2 = h1p[s2 * 32 + f2], u3 = h1p[s3 * 32 + f2];
        unsigned u4 = h1p[s4 * 32 + f2], u5 = h1p[s5 * 32 + f2];
        unsigned u6 = h1p[s6 * 32 + f2], u7 = h1p[s7 * 32 + f2];
        lo0 += (i0 < dg) ? lo_f(u0) : 0.f; hi0 += (i0 < dg) ? hi_f(u0) : 0.f;
        lo1 += (i1 < dg) ? lo_f(u1) : 0.f; hi1 += (i1 < dg) ? hi_f(u1) : 0.f;
        lo2 += (i2 < dg) ? lo_f(u2) : 0.f; hi2 += (i2 < dg) ? hi_f(u2) : 0.f;
        lo3 += (i3 < dg) ? lo_f(u3) : 0.f; hi3 += (i3 < dg) ? hi_f(u3) : 0.f;
        lo4 += (i4 < dg) ? lo_f(u4) : 0.f; hi4 += (i4 < dg) ? hi_f(u4) : 0.f;
        lo5 += (i5 < dg) ? lo_f(u5) : 0.f; hi5 += (i5 < dg) ? hi_f(u5) : 0.f;
        lo6 += (i6 < dg) ? lo_f(u6) : 0.f; hi6 += (i6 < dg) ? hi_f(u6) : 0.f;
        lo7 += (i7 < dg) ? lo_f(u7) : 0.f; hi7 += (i7 < dg) ? hi_f(u7) : 0.f;
    }
    float lo = ((lo0 + lo1) + (lo2 + lo3)) + ((lo4 + lo5) + (lo6 + lo7));
    float hi = ((hi0 + hi1) + (hi2 + hi3)) + ((hi4 + hi5) + (hi6 + hi7));
    lo += __shfl_xor(lo, 32, 64);
    hi += __shfl_xor(hi, 32, 64);
    if (eslot == 0) {
        unsigned us = h1p[node * 32 + f2];
        float dn = rsqrtf((float)(dg + 1));
        outp[node * 32 + f2] = pack2bf((lo + lo_f(us)) * dn, (hi + hi_f(us)) * dn);
    }
}

// ---------------- BN stats (bf16 input) ----------------

__global__ __launch_bounds__(256) void bnstats_k(const unsigned short* __restrict__ agg1b,
                                                 float* __restrict__ stats, int n) {
    int f = threadIdx.x & 63, g = threadIdx.x >> 6;
    float sum = 0.f, sq = 0.f;
    for (int r = blockIdx.x * 4 + g; r < n; r += gridDim.x * 4) {
        float v = bf2f(agg1b[r * 64 + f]);
        sum += v; sq += v * v;
    }
    __shared__ float s1[4][64], s2[4][64];
    s1[g][f] = sum; s2[g][f] = sq;
    __syncthreads();
    if (g == 0) {
        sum = s1[0][f] + s1[1][f] + s1[2][f] + s1[3][f];
        sq  = s2[0][f] + s2[1][f] + s2[2][f] + s2[3][f];
        atomicAdd(&stats[f], sum);
        atomicAdd(&stats[64 + f], sq);
    }
}

// ---------------- GEMM2 (MFMA bf16), BN fold inlined: h2s = bf16((relu(agg1b*s+t) @ W2) * dis[row]) ----------------

__global__ __launch_bounds__(256) void gemm2_k(const unsigned short* __restrict__ agg1b,
                                               const float* __restrict__ W2,
                                               const float* __restrict__ stats,
                                               const float* __restrict__ gamma, const float* __restrict__ beta,
                                               const float* __restrict__ dis,
                                               unsigned short* __restrict__ h2s, float invn, int n) {
    __shared__ unsigned short ab[64][72];    // +8 pad
    __shared__ unsigned short wt[32][72];
    __shared__ float s_s[64], s_t[64];
    int tid = threadIdx.x;
    int r0b = blockIdx.x * 64;
    if (tid < 64) {                          // BN fold (b1 cancels by shift invariance)
        float mean = stats[tid] * invn;
        float var = stats[64 + tid] * invn - mean * mean;
        float s = gamma[tid] * rsqrtf(var + BN_EPS);
        s_s[tid] = s;
        s_t[tid] = beta[tid] - mean * s;
    }
    for (int c = tid; c < 512; c += 256) {   // stage W2^T (512 float4)
        int k = c >> 3, n4 = (c & 7) * 4;
        float4 v = ((const float4*)W2)[c];
        wt[n4 + 0][k] = f2bf(v.x);
        wt[n4 + 1][k] = f2bf(v.y);
        wt[n4 + 2][k] = f2bf(v.z);
        wt[n4 + 3][k] = f2bf(v.w);
    }
    __syncthreads();
    for (int c = tid; c < 512; c += 256) {
        int r = c >> 3, k0 = (c & 7) * 8;
        int gr = r0b + r;
        unsigned short tmp[8];
        if (gr < n) {
            const unsigned short* ap = &agg1b[gr * 64 + k0];
            #pragma unroll
            for (int j = 0; j < 8; j++)
                tmp[j] = f2bf(fmaxf(bf2f(ap[j]) * s_s[k0 + j] + s_t[k0 + j], 0.f));
        } else {
            #pragma unroll
            for (int j = 0; j < 8; j++) tmp[j] = 0;
        }
        *(short8*)&ab[r][k0] = *(short8*)tmp;
    }
    __syncthreads();

    int w = tid >> 6, lane = tid & 63;
    int rr = lane & 15, q = lane >> 4;
    floatx4 acc0 = {0.f, 0.f, 0.f, 0.f}, acc1 = acc0;
    #pragma unroll
    for (int kt = 0; kt < 2; kt++) {
        int k0 = kt * 32 + q * 8;
        short8 a  = *(const short8*)&ab[w * 16 + rr][k0];
        short8 b0 = *(const short8*)&wt[rr][k0];
        short8 b1 = *(const short8*)&wt[16 + rr][k0];
        acc0 = __builtin_amdgcn_mfma_f32_16x16x32_bf16(a, b0, acc0, 0, 0, 0);
        acc1 = __builtin_amdgcn_mfma_f32_16x16x32_bf16(a, b1, acc1, 0, 0, 0);
    }
    #pragma unroll
    for (int t = 0; t < 4; t++) {
        int gr = r0b + w * 16 + q * 4 + t;
        if (gr < n) {
            float dd = dis[gr];
            h2s[gr * 32 + rr]      = f2bf(acc0[t] * dd);
            h2s[gr * 32 + 16 + rr] = f2bf(acc1[t] * dd);
        }
    }
}

// ---------------- Aggregation layer 2: node per half-wave, uint-packed (2 feats/lane, 2 edges/instr) ----------------

__global__ __launch_bounds__(256) void agg2_k(const unsigned* __restrict__ h2p,
                                              const int2* __restrict__ rpde,
                                              const int* __restrict__ col, const float* __restrict__ b2,
                                              float* __restrict__ out, int n) {
    int wave = (blockIdx.x * 256 + threadIdx.x) >> 6;
    int lane = threadIdx.x & 63;
    int half = lane >> 5, hl = lane & 31;
    int node = wave * 2 + half;
    if (node >= n) return;
    int f2 = hl & 15, eslot = hl >> 4;
    int2 rd = rpde[node];                    // uniform within half
    int e = rd.x, dg = rd.y;

    float lo0 = 0.f, lo1 = 0.f, lo2 = 0.f, lo3 = 0.f, lo4 = 0.f, lo5 = 0.f, lo6 = 0.f, lo7 = 0.f;
    float hi0 = 0.f, hi1 = 0.f, hi2 = 0.f, hi3 = 0.f, hi4 = 0.f, hi5 = 0.f, hi6 = 0.f, hi7 = 0.f;
    int b = 0;
    for (; b + 16 <= dg; b += 16) {
        int s0 = col[e + b + 0 + eslot],  s1 = col[e + b + 2 + eslot];
        int s2 = col[e + b + 4 + eslot],  s3 = col[e + b + 6 + eslot];
        int s4 = col[e + b + 8 + eslot],  s5 = col[e + b + 10 + eslot];
        int s6 = col[e + b + 12 + eslot], s7 = col[e + b + 14 + eslot];
        unsigned u0 = h2p[s0 * 16 + f2], u1 = h2p[s1 * 16 + f2];
        unsigned u2 = h2p[s2 * 16 + f2], u3 = h2p[s3 * 16 + f2];
        unsigned u4 = h2p[s4 * 16 + f2], u5 = h2p[s5 * 16 + f2];
        unsigned u6 = h2p[s6 * 16 + f2], u7 = h2p[s7 * 16 + f2];
        lo0 += lo_f(u0); hi0 += hi_f(u0);
        lo1 += lo_f(u1); hi1 += hi_f(u1);
        lo2 += lo_f(u2); hi2 += hi_f(u2);
        lo3 += lo_f(u3); hi3 += hi_f(u3);
        lo4 += lo_f(u4); hi4 += hi_f(u4);
        lo5 += lo_f(u5); hi5 += hi_f(u5);
        lo6 += lo_f(u6); hi6 += hi_f(u6);
        lo7 += lo_f(u7); hi7 += hi_f(u7);
    }
    if (b < dg) {
        int last = dg - 1;
        int i0 = b + 0 + eslot,  i1 = b + 2 + eslot,  i2 = b + 4 + eslot,  i3 = b + 6 + eslot;
        int i4 = b + 8 + eslot,  i5 = b + 10 + eslot, i6 = b + 12 + eslot, i7 = b + 14 + eslot;
        int s0 = col[e + min(i0, last)], s1 = col[e + min(i1, last)];
        int s2 = col[e + min(i2, last)], s3 = col[e + min(i3, last)];
        int s4 = col[e + min(i4, last)], s5 = col[e + min(i5, last)];
        int s6 = col[e + min(i6, last)], s7 = col[e + min(i7, last)];
        unsigned u0 = h2p[s0 * 16 + f2], u1 = h2p[s1 * 16 + f2];
        unsigned u2 = h2p[s2 * 16 + f2], u3 = h2p[s3 * 16 + f2];
        unsigned u4 = h2p[s4 * 16 + f2], u5 = h2p[s5 * 16 + f2];
        unsigned u6 = h2p[s6 * 16 + f2], u7 = h2p[s7 * 16 + f2];
        lo0 += (i0 < dg) ? lo_f(u0) : 0.f; hi0 += (i0 < dg) ? hi_f(u0) : 0.f;
        lo1 += (i1 < dg) ? lo_f(u1) : 0.f; hi1 += (i1 < dg) ? hi_f(u1) : 0.f;
        lo2 += (i2 < dg) ? lo_f(u2) : 0.f; hi2 += (i2 < dg) ? hi_f(u2) : 0.f;
        lo3 += (i3 < dg) ? lo_f(u3) : 0.f; hi3 += (i3 < dg) ? hi_f(u3) : 0.f;
        lo4 += (i4 < dg) ? lo_f(u4) : 0.f; hi4 += (i4 < dg) ? hi_f(u4) : 0.f;
        lo5 += (i5 < dg) ? lo_f(u5) : 0.f; hi5 += (i5 < dg) ? hi_f(u5) : 0.f;
        lo6 += (i6 < dg) ? lo_f(u6) : 0.f; hi6 += (i6 < dg) ? hi_f(u6) : 0.f;
        lo7 += (i7 < dg) ? lo_f(u7) : 0.f; hi7 += (i7 < dg) ? hi_f(u7) : 0.f;
    }
    float lo = ((lo0 + lo1) + (lo2 + lo3)) + ((lo4 + lo5) + (lo6 + lo7));
    float hi = ((hi0 + hi1) + (hi2 + hi3)) + ((hi4 + hi5) + (hi6 + hi7));
    lo += __shfl_xor(lo, 16, 64);            // cross-eslot within the 32-lane half
    hi += __shfl_xor(hi, 16, 64);
    if (eslot == 0) {
        unsigned us = h2p[node * 16 + f2];
        float dn = rsqrtf((float)(dg + 1));
        float2 bb = ((const float2*)b2)[f2];
        float2 o;
        o.x = (lo + lo_f(us)) * dn + bb.x;
        o.y = (hi + hi_f(us)) * dn + bb.y;
        ((float2*)out)[node * 16 + f2] = o;
    }
}

// ---------------- launch ----------------

extern "C" void kernel_launch(void* const* d_in, const int* in_sizes, int n_in,
                              void* d_out, int out_size, void* d_ws, size_t ws_size,
                              hipStream_t stream) {
    const float* x      = (const float*)d_in[0];
    const int*   ei     = (const int*)d_in[1];
    const float* W1     = (const float*)d_in[2];
    // d_in[3] = b1 (cancels inside BN)
    const float* gamma1 = (const float*)d_in[4];
    const float* beta1  = (const float*)d_in[5];
    const float* W2     = (const float*)d_in[6];
    const float* b2     = (const float*)d_in[7];
    float* out = (float*)d_out;

    int N = in_sizes[0] / DIN;
    int E = in_sizes[1] / 2;
    const int* src = ei;
    const int* dst = ei + E;
    int nbk = (N + BK - 1) >> BKSH;         // 782
    int chunk = (E + G - 1) / G;

    size_t off = 0;  // 4B units
    auto alloc = [&](size_t elems) -> void* {
        void* p = (char*)d_ws + off * 4;
        off += (elems + 127) & ~size_t(127);
        return p;
    };
    int*            hist_g = (int*)alloc((size_t)G * NBK_MAX);
    int*            rowoff = (int*)alloc((size_t)G * NBK_MAX);            // g-major [G][nbk]
    int*            tot    = (int*)alloc(NBK_MAX);
    unsigned*       recs   = (unsigned*)alloc((size_t)NBK_MAX * CAP);     // fixed-CAP regions
    int*            col    = (int*)alloc((size_t)NBK_MAX * CAP);
    float*          dis    = (float*)alloc(N);
    int2*           rpde   = (int2*)alloc((size_t)N * 2);
    float*          stats  = (float*)alloc(128);
    unsigned short* h1s    = (unsigned short*)alloc((size_t)N * DH / 2);  // bf16
    unsigned short* agg1b  = (unsigned short*)alloc((size_t)N * DH / 2);  // bf16
    unsigned short* h2s    = h1s;  // h1s dead after agg1_k

    hipMemsetAsync(stats, 0, 128 * sizeof(float), stream);

    hist_k<<<G, 512, 0, stream>>>(dst, hist_g, E, nbk, chunk);
    scan_k<<<(nbk + 15) / 16, 256, 0, stream>>>(hist_g, rowoff, tot, nbk);
    scatter_k<<<G, 512, 0, stream>>>(src, dst, rowoff, recs, E, nbk, chunk);
    csr_k<<<nbk, 256, 0, stream>>>(recs, tot, dis, rpde, col, N);

    gemm1_k<<<(N + 63) / 64, 256, 0, stream>>>(x, W1, dis, h1s, N);
    agg1_k<<<(N + 3) / 4, 256, 0, stream>>>((const unsigned*)h1s, rpde, col, (unsigned*)agg1b, N);

    bnstats_k<<<400, 256, 0, stream>>>(agg1b, stats, N);

    gemm2_k<<<(N + 63) / 64, 256, 0, stream>>>(agg1b, W2, stats, gamma1, beta1, dis, h2s,
                                               1.0f / (float)N, N);
    agg2_k<<<(N + 7) / 8, 256, 0, stream>>>((const unsigned*)h2s, rpde, col, b2, out, N);
}

// Round 15
// 251.921 us; speedup vs baseline: 1.1139x; 1.0095x over previous
//
#include <hip/hip_runtime.h>

#define DIN 128
#define DH 64
#define DOUT 32
#define BN_EPS 1e-5f

#define BK 128          // nodes per bucket
#define BKSH 7          // log2(BK)
#define NBK_MAX 784     // ceil(100000/128)=782, padded
#define G 256           // counting-sort partition blocks; 32/XCD open-line set ~3.2MB fits L2
#define CAP 2560        // fixed per-bucket region capacity (mean 2048, +11 sigma)

typedef __attribute__((ext_vector_type(8))) short short8;
typedef __attribute__((ext_vector_type(4))) float floatx4;

// bf16 helpers (RNE store, exact load)
__device__ __forceinline__ unsigned short f2bf(float f) {
    union { float f; unsigned u; } v; v.f = f;
    unsigned r = (v.u + 0x7FFFu + ((v.u >> 16) & 1u)) >> 16;
    return (unsigned short)r;
}
__device__ __forceinline__ float bf2f(unsigned short h) {
    union { unsigned u; float f; } v; v.u = ((unsigned)h) << 16;
    return v.f;
}
__device__ __forceinline__ float lo_f(unsigned u) {
    union { unsigned u; float f; } v; v.u = u << 16;
    return v.f;
}
__device__ __forceinline__ float hi_f(unsigned u) {
    union { unsigned u; float f; } v; v.u = u & 0xFFFF0000u;
    return v.f;
}
__device__ __forceinline__ unsigned pack2bf(float lo, float hi) {
    return (unsigned)f2bf(lo) | ((unsigned)f2bf(hi) << 16);
}

// ---------------- counting sort pass 1: per-block bucket histogram (g-major write) ----------------

__global__ __launch_bounds__(512) void hist_k(const int* __restrict__ dst, int* __restrict__ hist_g,
                                              int E, int nbk, int chunk) {
    __shared__ int hist[NBK_MAX];
    int g = blockIdx.x, tid = threadIdx.x;
    for (int b = tid; b < nbk; b += 512) hist[b] = 0;
    __syncthreads();
    int i0 = g * chunk, iend = min(i0 + chunk, E);
    for (int i = i0 + tid; i < iend; i += 512)
        atomicAdd(&hist[dst[i] >> BKSH], 1);
    __syncthreads();
    for (int b = tid; b < nbk; b += 512)
        hist_g[(size_t)g * nbk + b] = hist[b];   // coalesced row write
}

// ---------------- pass 2: per-bucket exclusive scan over the G=256 block-counts ----------------

__global__ __launch_bounds__(256) void scan_k(const int* __restrict__ hist_g, int* __restrict__ rowoff,
                                              int* __restrict__ tot, int nbk) {
    __shared__ int seg[16][17];
    int tid = threadIdx.x;
    int gl = tid >> 4, bl = tid & 15;
    int b = blockIdx.x * 16 + bl;
    bool bok = b < nbk;
    int vals[16];
    int psum = 0;
    #pragma unroll
    for (int j = 0; j < 16; j++) {
        int g = gl * 16 + j;
        int v = bok ? hist_g[(size_t)g * nbk + b] : 0;   // 16 independent loads in flight
        vals[j] = v; psum += v;
    }
    seg[gl][bl] = psum;
    __syncthreads();
    #pragma unroll
    for (int off = 1; off < 16; off <<= 1) {
        int t = (gl >= off) ? seg[gl - off][bl] : 0;
        __syncthreads();
        seg[gl][bl] += t;
        __syncthreads();
    }
    int run = seg[gl][bl] - psum;                        // exclusive base of this 16-g segment
    if (gl == 15 && bok) tot[b] = seg[15][bl];
    #pragma unroll
    for (int j = 0; j < 16; j++) {
        int g = gl * 16 + j;
        if (bok) rowoff[(size_t)g * nbk + b] = run;      // g-major: scatter_k reads rows coalesced
        run += vals[j];
    }
}

// ---------------- pass 3: scatter records into fixed-CAP bucket regions (no global atomics) ----------------

__global__ __launch_bounds__(512) void scatter_k(const int* __restrict__ src, const int* __restrict__ dst,
                                                 const int* __restrict__ rowoff,
                                                 unsigned* __restrict__ recs, int E, int nbk, int chunk) {
    __shared__ int cur[NBK_MAX];
    int g = blockIdx.x, tid = threadIdx.x;
    for (int b = tid; b < nbk; b += 512)
        cur[b] = b * CAP + rowoff[(size_t)g * nbk + b];   // coalesced row read (g-major)
    __syncthreads();
    int i0 = g * chunk, iend = min(i0 + chunk, E);
    for (int i = i0 + tid; i < iend; i += 512) {
        int s = src[i], d = dst[i];
        int b = d >> BKSH;
        int slot = atomicAdd(&cur[b], 1);   // LDS atomic
        if (slot < (b + 1) * CAP)           // overflow guard (never fires at CAP=mean+11sigma)
            recs[slot] = ((unsigned)s << BKSH) | (unsigned)(d & (BK - 1));
    }
}

// ---------------- pass 4: within-bucket node sort -> CSR, wave-private histograms/cursors ----------------
// 8 waves: wave w owns slice e = lo + w*64 + lane (step 512). deg8[w][dl] private histogram;
// wb[w][dl] = bas[dl] + prefix of waves <w, used directly as the wave's private scatter cursor.
// LDS atomic conflict degree drops 8x vs block-shared counters.

__global__ __launch_bounds__(512) void csr_k(const unsigned* __restrict__ recs, const int* __restrict__ tot,
                                             float* __restrict__ dis, int2* __restrict__ rpde,
                                             int* __restrict__ col, int n) {
    __shared__ int deg8[8][BK];   // 4 KB
    __shared__ int wb[8][BK];     // 4 KB
    __shared__ int deg[BK], sc[BK], bas[BK];
    int b = blockIdx.x, tid = threadIdx.x;
    int w = tid >> 6, lane = tid & 63;
    for (int i = tid; i < 8 * BK; i += 512) ((int*)deg8)[i] = 0;
    __syncthreads();
    int lo = b * CAP;
    int ne = min(tot[b], CAP);
    int hi = lo + ne;
    for (int e = lo + w * 64 + lane; e < hi; e += 512)
        atomicAdd(&deg8[w][recs[e] & (BK - 1)], 1);
    __syncthreads();
    if (tid < BK) {
        int run = 0;
        #pragma unroll
        for (int ww = 0; ww < 8; ww++) { wb[ww][tid] = run; run += deg8[ww][tid]; }
        deg[tid] = run; sc[tid] = run;
    }
    __syncthreads();
    for (int off = 1; off < BK; off <<= 1) {
        int t = (tid < BK && tid >= off) ? sc[tid - off] : 0;
        __syncthreads();
        if (tid < BK) sc[tid] += t;
        __syncthreads();
    }
    if (tid < BK) {
        bas[tid] = sc[tid] - deg[tid];
        int g = b * BK + tid;
        if (g < n) {
            dis[g] = rsqrtf((float)(deg[tid] + 1));   // +1 self-loop
            rpde[g] = make_int2(lo + bas[tid], deg[tid]);
        }
    }
    __syncthreads();
    for (int i = tid; i < 8 * BK; i += 512)
        ((int*)wb)[i] += bas[i & (BK - 1)];           // wb[w][dl] += bas[dl]
    __syncthreads();
    for (int e = lo + w * 64 + lane; e < hi; e += 512) {
        unsigned r = recs[e];
        int dl = r & (BK - 1);
        int k = atomicAdd(&wb[w][dl], 1);             // wave-private cursor
        col[lo + k] = (int)(r >> BKSH);
    }
}

// ---------------- GEMM1 (MFMA bf16): h1s = bf16((x @ W1) * dis[row]) ----------------

__global__ __launch_bounds__(256) void gemm1_k(const float* __restrict__ x,
                                               const float* __restrict__ W1,
                                               const float* __restrict__ dis,
                                               unsigned short* __restrict__ h1s, int n) {
    __shared__ unsigned short xb[64][136];   // +8 pad: rows 272B apart -> 2-way bank alias (free)
    __shared__ unsigned short wt[64][136];
    int tid = threadIdx.x;
    int r0b = blockIdx.x * 64;

    for (int c = tid; c < 2048; c += 256) {
        int k = c >> 4, n4 = (c & 15) * 4;
        float4 v = ((const float4*)W1)[c];
        wt[n4 + 0][k] = f2bf(v.x);
        wt[n4 + 1][k] = f2bf(v.y);
        wt[n4 + 2][k] = f2bf(v.z);
        wt[n4 + 3][k] = f2bf(v.w);
    }
    for (int c = tid; c < 2048; c += 256) {
        int r = c >> 5, k4 = (c & 31) * 4;
        int gr = r0b + r;
        float4 v = make_float4(0.f, 0.f, 0.f, 0.f);
        if (gr < n) v = ((const float4*)x)[(gr << 5) + (k4 >> 2)];
        ushort4 o;
        o.x = f2bf(v.x); o.y = f2bf(v.y); o.z = f2bf(v.z); o.w = f2bf(v.w);
        *(ushort4*)&xb[r][k4] = o;
    }
    __syncthreads();

    int w = tid >> 6, lane = tid & 63;
    int rr = lane & 15, q = lane >> 4;
    floatx4 acc0 = {0.f, 0.f, 0.f, 0.f}, acc1 = acc0, acc2 = acc0, acc3 = acc0;
    #pragma unroll
    for (int kt = 0; kt < 4; kt++) {
        int k0 = kt * 32 + q * 8;
        short8 a  = *(const short8*)&xb[w * 16 + rr][k0];
        short8 b0 = *(const short8*)&wt[rr][k0];
        short8 b1 = *(const short8*)&wt[16 + rr][k0];
        short8 b2 = *(const short8*)&wt[32 + rr][k0];
        short8 b3 = *(const short8*)&wt[48 + rr][k0];
        acc0 = __builtin_amdgcn_mfma_f32_16x16x32_bf16(a, b0, acc0, 0, 0, 0);
        acc1 = __builtin_amdgcn_mfma_f32_16x16x32_bf16(a, b1, acc1, 0, 0, 0);
        acc2 = __builtin_amdgcn_mfma_f32_16x16x32_bf16(a, b2, acc2, 0, 0, 0);
        acc3 = __builtin_amdgcn_mfma_f32_16x16x32_bf16(a, b3, acc3, 0, 0, 0);
    }
    #pragma unroll
    for (int t = 0; t < 4; t++) {
        int gr = r0b + w * 16 + q * 4 + t;
        if (gr < n) {
            float dd = dis[gr];
            unsigned short* o = &h1s[gr * 64];
            o[rr]      = f2bf(acc0[t] * dd);
            o[16 + rr] = f2bf(acc1[t] * dd);
            o[32 + rr] = f2bf(acc2[t] * dd);
            o[48 + rr] = f2bf(acc3[t] * dd);
        }
    }
}

// ---------------- Aggregation layer 1: wave per node, uint-packed (2 feats/lane, 2 edges/instr) ----------------

__global__ __launch_bounds__(256) void agg1_k(const unsigned* __restrict__ h1p,
                                              const int2* __restrict__ rpde,
                                              const int* __restrict__ col,
                                              unsigned* __restrict__ outp, int n) {
    int node = (blockIdx.x * 256 + threadIdx.x) >> 6;
    int lane = threadIdx.x & 63;
    if (node >= n) return;
    int f2 = lane & 31, eslot = lane >> 5;
    int2 rd = rpde[node];
    int e  = __builtin_amdgcn_readfirstlane(rd.x);
    int dg = __builtin_amdgcn_readfirstlane(rd.y);

    float lo0 = 0.f, lo1 = 0.f, lo2 = 0.f, lo3 = 0.f, lo4 = 0.f, lo5 = 0.f, lo6 = 0.f, lo7 = 0.f;
    float hi0 = 0.f, hi1 = 0.f, hi2 = 0.f, hi3 = 0.f, hi4 = 0.f, hi5 = 0.f, hi6 = 0.f, hi7 = 0.f;
    int b = 0;
    for (; b + 16 <= dg; b += 16) {
        int s0 = col[e + b + 0 + eslot],  s1 = col[e + b + 2 + eslot];
        int s2 = col[e + b + 4 + eslot],  s3 = col[e + b + 6 + eslot];
        int s4 = col[e + b + 8 + eslot],  s5 = col[e + b + 10 + eslot];
        int s6 = col[e + b + 12 + eslot], s7 = col[e + b + 14 + eslot];
        unsigned u0 = h1p[s0 * 32 + f2], u1 = h1p[s1 * 32 + f2];
        unsigned u2 = h1p[s2 * 32 + f2], u3 = h1p[s3 * 32 + f2];
        unsigned u4 = h1p[s4 * 32 + f2], u5 = h1p[s5 * 32 + f2];
        unsigned u6 = h1p[s6 * 32 + f2], u7 = h1p[s7 * 32 + f2];
        lo0 += lo_f(u0); hi0 += hi_f(u0);
        lo1 += lo_f(u1); hi1 += hi_f(u1);
        lo2 += lo_f(u2); hi2 += hi_f(u2);
        lo3 += lo_f(u3); hi3 += hi_f(u3);
        lo4 += lo_f(u4); hi4 += hi_f(u4);
        lo5 += lo_f(u5); hi5 += hi_f(u5);
        lo6 += lo_f(u6); hi6 += hi_f(u6);
        lo7 += lo_f(u7); hi7 += hi_f(u7);
    }
    if (b < dg) {
        int last = dg - 1;
        int i0 = b + 0 + eslot,  i1 = b + 2 + eslot,  i2 = b + 4 + eslot,  i3 = b + 6 + eslot;
        int i4 = b + 8 + eslot,  i5 = b + 10 + eslot, i6 = b + 12 + eslot, i7 = b + 14 + eslot;
        int s0 = col[e + min(i0, last)], s1 = col[e + min(i1, last)];
        int s2 = col[e + min(i2, last)], s3 = col[e + min(i3, last)];
        int s4 = col[e + min(i4, last)], s5 = col[e + min(i5, last)];
        int s6 = col[e + min(i6, last)], s7 = col[e + min(i7, last)];
        unsigned u0 = h1p[s0 * 32 + f2], u1 = h1p[s1 * 32 + f2];
        unsigned u2 = h1p[s2 * 32 + f2], u3 = h1p[s3 * 32 + f2];
        unsigned u4 = h1p[s4 * 32 + f2], u5 = h1p[s5 * 32 + f2];
        unsigned u6 = h1p[s6 * 32 + f2], u7 = h1p[s7 * 32 + f2];
        lo0 += (i0 < dg) ? lo_f(u0) : 0.f; hi0 += (i0 < dg) ? hi_f(u0) : 0.f;
        lo1 += (i1 < dg) ? lo_f(u1) : 0.f; hi1 += (i1 < dg) ? hi_f(u1) : 0.f;
        lo2 += (i2 < dg) ? lo_f(u2) : 0.f; hi2 += (i2 < dg) ? hi_f(u2) : 0.f;
        lo3 += (i3 < dg) ? lo_f(u3) : 0.f; hi3 += (i3 < dg) ? hi_f(u3) : 0.f;
        lo4 += (i4 < dg) ? lo_f(u4) : 0.f; hi4 += (i4 < dg) ? hi_f(u4) : 0.f;
        lo5 += (i5 < dg) ? lo_f(u5) : 0.f; hi5 += (i5 < dg) ? hi_f(u5) : 0.f;
        lo6 += (i6 < dg) ? lo_f(u6) : 0.f; hi6 += (i6 < dg) ? hi_f(u6) : 0.f;
        lo7 += (i7 < dg) ? lo_f(u7) : 0.f; hi7 += (i7 < dg) ? hi_f(u7) : 0.f;
    }
    float lo = ((lo0 + lo1) + (lo2 + lo3)) + ((lo4 + lo5) + (lo6 + lo7));
    float hi = ((hi0 + hi1) + (hi2 + hi3)) + ((hi4 + hi5) + (hi6 + hi7));
    lo += __shfl_xor(lo, 32, 64);
    hi += __shfl_xor(hi, 32, 64);
    if (eslot == 0) {
        unsigned us = h1p[node * 32 + f2];
        float dn = rsqrtf((float)(dg + 1));
        outp[node * 32 + f2] = pack2bf((lo + lo_f(us)) * dn, (hi + hi_f(us)) * dn);
    }
}

// ---------------- BN stats (bf16 input) ----------------

__global__ __launch_bounds__(256) void bnstats_k(const unsigned short* __restrict__ agg1b,
                                                 float* __restrict__ stats, int n) {
    int f = threadIdx.x & 63, g = threadIdx.x >> 6;
    float sum = 0.f, sq = 0.f;
    for (int r = blockIdx.x * 4 + g; r < n; r += gridDim.x * 4) {
        float v = bf2f(agg1b[r * 64 + f]);
        sum += v; sq += v * v;
    }
    __shared__ float s1[4][64], s2[4][64];
    s1[g][f] = sum; s2[g][f] = sq;
    __syncthreads();
    if (g == 0) {
        sum = s1[0][f] + s1[1][f] + s1[2][f] + s1[3][f];
        sq  = s2[0][f] + s2[1][f] + s2[2][f] + s2[3][f];
        atomicAdd(&stats[f], sum);
        atomicAdd(&stats[64 + f], sq);
    }
}

// ---------------- GEMM2 (MFMA bf16), BN fold inlined: h2s = bf16((relu(agg1b*s+t) @ W2) * dis[row]) ----------------

__global__ __launch_bounds__(256) void gemm2_k(const unsigned short* __restrict__ agg1b,
                                               const float* __restrict__ W2,
                                               const float* __restrict__ stats,
                                               const float* __restrict__ gamma, const float* __restrict__ beta,
                                               const float* __restrict__ dis,
                                               unsigned short* __restrict__ h2s, float invn, int n) {
    __shared__ unsigned short ab[64][72];    // +8 pad
    __shared__ unsigned short wt[32][72];
    __shared__ float s_s[64], s_t[64];
    int tid = threadIdx.x;
    int r0b = blockIdx.x * 64;
    if (tid < 64) {                          // BN fold (b1 cancels by shift invariance)
        float mean = stats[tid] * invn;
        float var = stats[64 + tid] * invn - mean * mean;
        float s = gamma[tid] * rsqrtf(var + BN_EPS);
        s_s[tid] = s;
        s_t[tid] = beta[tid] - mean * s;
    }
    for (int c = tid; c < 512; c += 256) {   // stage W2^T (512 float4)
        int k = c >> 3, n4 = (c & 7) * 4;
        float4 v = ((const float4*)W2)[c];
        wt[n4 + 0][k] = f2bf(v.x);
        wt[n4 + 1][k] = f2bf(v.y);
        wt[n4 + 2][k] = f2bf(v.z);
        wt[n4 + 3][k] = f2bf(v.w);
    }
    __syncthreads();
    for (int c = tid; c < 512; c += 256) {
        int r = c >> 3, k0 = (c & 7) * 8;
        int gr = r0b + r;
        unsigned short tmp[8];
        if (gr < n) {
            const unsigned short* ap = &agg1b[gr * 64 + k0];
            #pragma unroll
            for (int j = 0; j < 8; j++)
                tmp[j] = f2bf(fmaxf(bf2f(ap[j]) * s_s[k0 + j] + s_t[k0 + j], 0.f));
        } else {
            #pragma unroll
            for (int j = 0; j < 8; j++) tmp[j] = 0;
        }
        *(short8*)&ab[r][k0] = *(short8*)tmp;
    }
    __syncthreads();

    int w = tid >> 6, lane = tid & 63;
    int rr = lane & 15, q = lane >> 4;
    floatx4 acc0 = {0.f, 0.f, 0.f, 0.f}, acc1 = acc0;
    #pragma unroll
    for (int kt = 0; kt < 2; kt++) {
        int k0 = kt * 32 + q * 8;
        short8 a  = *(const short8*)&ab[w * 16 + rr][k0];
        short8 b0 = *(const short8*)&wt[rr][k0];
        short8 b1 = *(const short8*)&wt[16 + rr][k0];
        acc0 = __builtin_amdgcn_mfma_f32_16x16x32_bf16(a, b0, acc0, 0, 0, 0);
        acc1 = __builtin_amdgcn_mfma_f32_16x16x32_bf16(a, b1, acc1, 0, 0, 0);
    }
    #pragma unroll
    for (int t = 0; t < 4; t++) {
        int gr = r0b + w * 16 + q * 4 + t;
        if (gr < n) {
            float dd = dis[gr];
            h2s[gr * 32 + rr]      = f2bf(acc0[t] * dd);
            h2s[gr * 32 + 16 + rr] = f2bf(acc1[t] * dd);
        }
    }
}

// ---------------- Aggregation layer 2: node per half-wave, uint-packed (2 feats/lane, 2 edges/instr) ----------------

__global__ __launch_bounds__(256) void agg2_k(const unsigned* __restrict__ h2p,
                                              const int2* __restrict__ rpde,
                                              const int* __restrict__ col, const float* __restrict__ b2,
                                              float* __restrict__ out, int n) {
    int wave = (blockIdx.x * 256 + threadIdx.x) >> 6;
    int lane = threadIdx.x & 63;
    int half = lane >> 5, hl = lane & 31;
    int node = wave * 2 + half;
    if (node >= n) return;
    int f2 = hl & 15, eslot = hl >> 4;
    int2 rd = rpde[node];                    // uniform within half
    int e = rd.x, dg = rd.y;

    float lo0 = 0.f, lo1 = 0.f, lo2 = 0.f, lo3 = 0.f, lo4 = 0.f, lo5 = 0.f, lo6 = 0.f, lo7 = 0.f;
    float hi0 = 0.f, hi1 = 0.f, hi2 = 0.f, hi3 = 0.f, hi4 = 0.f, hi5 = 0.f, hi6 = 0.f, hi7 = 0.f;
    int b = 0;
    for (; b + 16 <= dg; b += 16) {
        int s0 = col[e + b + 0 + eslot],  s1 = col[e + b + 2 + eslot];
        int s2 = col[e + b + 4 + eslot],  s3 = col[e + b + 6 + eslot];
        int s4 = col[e + b + 8 + eslot],  s5 = col[e + b + 10 + eslot];
        int s6 = col[e + b + 12 + eslot], s7 = col[e + b + 14 + eslot];
        unsigned u0 = h2p[s0 * 16 + f2], u1 = h2p[s1 * 16 + f2];
        unsigned u2 = h2p[s2 * 16 + f2], u3 = h2p[s3 * 16 + f2];
        unsigned u4 = h2p[s4 * 16 + f2], u5 = h2p[s5 * 16 + f2];
        unsigned u6 = h2p[s6 * 16 + f2], u7 = h2p[s7 * 16 + f2];
        lo0 += lo_f(u0); hi0 += hi_f(u0);
        lo1 += lo_f(u1); hi1 += hi_f(u1);
        lo2 += lo_f(u2); hi2 += hi_f(u2);
        lo3 += lo_f(u3); hi3 += hi_f(u3);
        lo4 += lo_f(u4); hi4 += hi_f(u4);
        lo5 += lo_f(u5); hi5 += hi_f(u5);
        lo6 += lo_f(u6); hi6 += hi_f(u6);
        lo7 += lo_f(u7); hi7 += hi_f(u7);
    }
    if (b < dg) {
        int last = dg - 1;
        int i0 = b + 0 + eslot,  i1 = b + 2 + eslot,  i2 = b + 4 + eslot,  i3 = b + 6 + eslot;
        int i4 = b + 8 + eslot,  i5 = b + 10 + eslot, i6 = b + 12 + eslot, i7 = b + 14 + eslot;
        int s0 = col[e + min(i0, last)], s1 = col[e + min(i1, last)];
        int s2 = col[e + min(i2, last)], s3 = col[e + min(i3, last)];
        int s4 = col[e + min(i4, last)], s5 = col[e + min(i5, last)];
        int s6 = col[e + min(i6, last)], s7 = col[e + min(i7, last)];
        unsigned u0 = h2p[s0 * 16 + f2], u1 = h2p[s1 * 16 + f2];
        unsigned u2 = h2p[s2 * 16 + f2], u3 = h2p[s3 * 16 + f2];
        unsigned u4 = h2p[s4 * 16 + f2], u5 = h2p[s5 * 16 + f2];
        unsigned u6 = h2p[s6 * 16 + f2], u7 = h2p[s7 * 16 + f2];
        lo0 += (i0 < dg) ? lo_f(u0) : 0.f; hi0 += (i0 < dg) ? hi_f(u0) : 0.f;
        lo1 += (i1 < dg) ? lo_f(u1) : 0.f; hi1 += (i1 < dg) ? hi_f(u1) : 0.f;
        lo2 += (i2 < dg) ? lo_f(u2) : 0.f; hi2 += (i2 < dg) ? hi_f(u2) : 0.f;
        lo3 += (i3 < dg) ? lo_f(u3) : 0.f; hi3 += (i3 < dg) ? hi_f(u3) : 0.f;
        lo4 += (i4 < dg) ? lo_f(u4) : 0.f; hi4 += (i4 < dg) ? hi_f(u4) : 0.f;
        lo5 += (i5 < dg) ? lo_f(u5) : 0.f; hi5 += (i5 < dg) ? hi_f(u5) : 0.f;
        lo6 += (i6 < dg) ? lo_f(u6) : 0.f; hi6 += (i6 < dg) ? hi_f(u6) : 0.f;
        lo7 += (i7 < dg) ? lo_f(u7) : 0.f; hi7 += (i7 < dg) ? hi_f(u7) : 0.f;
    }
    float lo = ((lo0 + lo1) + (lo2 + lo3)) + ((lo4 + lo5) + (lo6 + lo7));
    float hi = ((hi0 + hi1) + (hi2 + hi3)) + ((hi4 + hi5) + (hi6 + hi7));
    lo += __shfl_xor(lo, 16, 64);            // cross-eslot within the 32-lane half
    hi += __shfl_xor(hi, 16, 64);
    if (eslot == 0) {
        unsigned us = h2p[node * 16 + f2];
        float dn = rsqrtf((float)(dg + 1));
        float2 bb = ((const float2*)b2)[f2];
        float2 o;
        o.x = (lo + lo_f(us)) * dn + bb.x;
        o.y = (hi + hi_f(us)) * dn + bb.y;
        ((float2*)out)[node * 16 + f2] = o;
    }
}

// ---------------- launch ----------------

extern "C" void kernel_launch(void* const* d_in, const int* in_sizes, int n_in,
                              void* d_out, int out_size, void* d_ws, size_t ws_size,
                              hipStream_t stream) {
    const float* x      = (const float*)d_in[0];
    const int*   ei     = (const int*)d_in[1];
    const float* W1     = (const float*)d_in[2];
    // d_in[3] = b1 (cancels inside BN)
    const float* gamma1 = (const float*)d_in[4];
    const float* beta1  = (const float*)d_in[5];
    const float* W2     = (const float*)d_in[6];
    const float* b2     = (const float*)d_in[7];
    float* out = (float*)d_out;

    int N = in_sizes[0] / DIN;
    int E = in_sizes[1] / 2;
    const int* src = ei;
    const int* dst = ei + E;
    int nbk = (N + BK - 1) >> BKSH;         // 782
    int chunk = (E + G - 1) / G;

    size_t off = 0;  // 4B units
    auto alloc = [&](size_t elems) -> void* {
        void* p = (char*)d_ws + off * 4;
        off += (elems + 127) & ~size_t(127);
        return p;
    };
    int*            hist_g = (int*)alloc((size_t)G * NBK_MAX);
    int*            rowoff = (int*)alloc((size_t)G * NBK_MAX);            // g-major [G][nbk]
    int*            tot    = (int*)alloc(NBK_MAX);
    unsigned*       recs   = (unsigned*)alloc((size_t)NBK_MAX * CAP);     // fixed-CAP regions
    int*            col    = (int*)alloc((size_t)NBK_MAX * CAP);
    float*          dis    = (float*)alloc(N);
    int2*           rpde   = (int2*)alloc((size_t)N * 2);
    float*          stats  = (float*)alloc(128);
    unsigned short* h1s    = (unsigned short*)alloc((size_t)N * DH / 2);  // bf16
    unsigned short* agg1b  = (unsigned short*)alloc((size_t)N * DH / 2);  // bf16
    unsigned short* h2s    = h1s;  // h1s dead after agg1_k

    hipMemsetAsync(stats, 0, 128 * sizeof(float), stream);

    hist_k<<<G, 512, 0, stream>>>(dst, hist_g, E, nbk, chunk);
    scan_k<<<(nbk + 15) / 16, 256, 0, stream>>>(hist_g, rowoff, tot, nbk);
    scatter_k<<<G, 512, 0, stream>>>(src, dst, rowoff, recs, E, nbk, chunk);
    csr_k<<<nbk, 512, 0, stream>>>(recs, tot, dis, rpde, col, N);

    gemm1_k<<<(N + 63) / 64, 256, 0, stream>>>(x, W1, dis, h1s, N);
    agg1_k<<<(N + 3) / 4, 256, 0, stream>>>((const unsigned*)h1s, rpde, col, (unsigned*)agg1b, N);

    bnstats_k<<<400, 256, 0, stream>>>(agg1b, stats, N);

    gemm2_k<<<(N + 63) / 64, 256, 0, stream>>>(agg1b, W2, stats, gamma1, beta1, dis, h2s,
                                               1.0f / (float)N, N);
    agg2_k<<<(N + 7) / 8, 256, 0, stream>>>((const unsigned*)h2s, rpde, col, b2, out, N);
}